// Round 1
// baseline (241.183 us; speedup 1.0000x reference)
//
#include <hip/hip_runtime.h>

// Causal depthwise conv1d: y[b,s,h] = sum_j x[b, s-(K-1)+j, h] * w[h,j], * mask[b,s]
// B=4, S=4096, H=2048, K=4, fp32. Memory-bound; sliding-window register reuse.

constexpr int B_  = 4;
constexpr int S_  = 4096;
constexpr int H_  = 2048;
constexpr int K_  = 4;
constexpr int T_  = 64;          // s-positions per block chunk (3/T re-read overhead)
constexpr int H4_ = H_ / 4;      // 512 float4 channel-groups per (b,s) row
constexpr int TPB = 256;

__global__ __launch_bounds__(TPB) void budgie_dwconv1d_kernel(
    const float* __restrict__ x,     // [B,S,H]
    const float* __restrict__ w,     // [H,K]
    const float* __restrict__ mask,  // [B,S]
    float* __restrict__ y)           // [B,S,H]
{
    const int h4 = blockIdx.x * TPB + threadIdx.x;   // channel-group id, 0..H4_-1
    const int s0 = blockIdx.y * T_;
    const int b  = blockIdx.z;

    const float4* __restrict__ x4 = (const float4*)x;
    const float4* __restrict__ w4 = (const float4*)w;
    float4* __restrict__ y4 = (float4*)y;

    // Per-channel taps: w[h, 0..3] is contiguous -> one float4 per channel.
    const int hbase = h4 * 4;
    const float4 w0 = w4[hbase + 0];
    const float4 w1 = w4[hbase + 1];
    const float4 w2 = w4[hbase + 2];
    const float4 w3 = w4[hbase + 3];

    const long base = (long)b * S_ * H4_ + h4;       // float4-unit index at s=0

    const float4 zero4 = make_float4(0.f, 0.f, 0.f, 0.f);
    // Preload sliding window x[s0-3], x[s0-2], x[s0-1] (zeros left of s=0).
    float4 xm3 = (s0 >= 3) ? x4[base + (long)(s0 - 3) * H4_] : zero4;
    float4 xm2 = (s0 >= 2) ? x4[base + (long)(s0 - 2) * H4_] : zero4;
    float4 xm1 = (s0 >= 1) ? x4[base + (long)(s0 - 1) * H4_] : zero4;

    #pragma unroll 4
    for (int t = 0; t < T_; ++t) {
        const int s = s0 + t;
        const float4 x0 = x4[base + (long)s * H4_];
        const float  m  = mask[b * S_ + s];

        float4 o;
        // channel c: y = x[s-3]*w[c].x + x[s-2]*w[c].y + x[s-1]*w[c].z + x[s]*w[c].w
        o.x = fmaf(xm3.x, w0.x, fmaf(xm2.x, w0.y, fmaf(xm1.x, w0.z, x0.x * w0.w)));
        o.y = fmaf(xm3.y, w1.x, fmaf(xm2.y, w1.y, fmaf(xm1.y, w1.z, x0.y * w1.w)));
        o.z = fmaf(xm3.z, w2.x, fmaf(xm2.z, w2.y, fmaf(xm1.z, w2.z, x0.z * w2.w)));
        o.w = fmaf(xm3.w, w3.x, fmaf(xm2.w, w3.y, fmaf(xm1.w, w3.z, x0.w * w3.w)));
        o.x *= m; o.y *= m; o.z *= m; o.w *= m;

        y4[base + (long)s * H4_] = o;

        xm3 = xm2; xm2 = xm1; xm1 = x0;
    }
}

extern "C" void kernel_launch(void* const* d_in, const int* in_sizes, int n_in,
                              void* d_out, int out_size, void* d_ws, size_t ws_size,
                              hipStream_t stream) {
    const float* x    = (const float*)d_in[0];   // hidden_states [B,S,H]
    const float* w    = (const float*)d_in[1];   // weight [H,K]
    const float* mask = (const float*)d_in[2];   // attention_mask_2d [B,S]
    float* y = (float*)d_out;

    dim3 grid(H4_ / TPB, S_ / T_, B_);           // (2, 64, 4)
    budgie_dwconv1d_kernel<<<grid, TPB, 0, stream>>>(x, w, mask, y);
}

// Round 2
// 240.826 us; speedup vs baseline: 1.0015x; 1.0015x over previous
//
#include <hip/hip_runtime.h>

// Causal depthwise conv1d: y[b,s,h] = sum_j x[b, s-(K-1)+j, h] * w[h,j], * mask[b,s]
// B=4, S=4096, H=2048, K=4, fp32. Memory-bound; sliding-window register reuse.
// R1->R2: T 64->16 (grid 512->2048 blocks, 8->32 waves/CU) to fix latency-bound
// occupancy (was 18.6%, 2.4 TB/s). Re-read overhead 3/16 lands in L2/L3.

constexpr int B_  = 4;
constexpr int S_  = 4096;
constexpr int H_  = 2048;
constexpr int T_  = 16;          // s-positions per block chunk
constexpr int H4_ = H_ / 4;      // 512 float4 channel-groups per (b,s) row
constexpr int TPB = 256;

__global__ __launch_bounds__(TPB) void budgie_dwconv1d_kernel(
    const float* __restrict__ x,     // [B,S,H]
    const float* __restrict__ w,     // [H,K]
    const float* __restrict__ mask,  // [B,S]
    float* __restrict__ y)           // [B,S,H]
{
    const int h4 = blockIdx.x * TPB + threadIdx.x;   // channel-group id, 0..H4_-1
    const int s0 = blockIdx.y * T_;
    const int b  = blockIdx.z;

    const float4* __restrict__ x4 = (const float4*)x;
    const float4* __restrict__ w4 = (const float4*)w;
    float4* __restrict__ y4 = (float4*)y;

    // Per-channel taps: w[h, 0..3] is contiguous -> one float4 per channel.
    const int hbase = h4 * 4;
    const float4 w0 = w4[hbase + 0];
    const float4 w1 = w4[hbase + 1];
    const float4 w2 = w4[hbase + 2];
    const float4 w3 = w4[hbase + 3];

    const long base = (long)b * S_ * H4_ + h4;       // float4-unit index at s=0

    const float4 zero4 = make_float4(0.f, 0.f, 0.f, 0.f);
    // Preload sliding window x[s0-3], x[s0-2], x[s0-1] (zeros left of s=0).
    float4 xm3 = (s0 >= 3) ? x4[base + (long)(s0 - 3) * H4_] : zero4;
    float4 xm2 = (s0 >= 2) ? x4[base + (long)(s0 - 2) * H4_] : zero4;
    float4 xm1 = (s0 >= 1) ? x4[base + (long)(s0 - 1) * H4_] : zero4;

    #pragma unroll 8
    for (int t = 0; t < T_; ++t) {
        const int s = s0 + t;
        const float4 x0 = x4[base + (long)s * H4_];
        const float  m  = mask[b * S_ + s];

        float4 o;
        // channel c: y = x[s-3]*w[c].x + x[s-2]*w[c].y + x[s-1]*w[c].z + x[s]*w[c].w
        o.x = fmaf(xm3.x, w0.x, fmaf(xm2.x, w0.y, fmaf(xm1.x, w0.z, x0.x * w0.w)));
        o.y = fmaf(xm3.y, w1.x, fmaf(xm2.y, w1.y, fmaf(xm1.y, w1.z, x0.y * w1.w)));
        o.z = fmaf(xm3.z, w2.x, fmaf(xm2.z, w2.y, fmaf(xm1.z, w2.z, x0.z * w2.w)));
        o.w = fmaf(xm3.w, w3.x, fmaf(xm2.w, w3.y, fmaf(xm1.w, w3.z, x0.w * w3.w)));
        o.x *= m; o.y *= m; o.z *= m; o.w *= m;

        y4[base + (long)s * H4_] = o;

        xm3 = xm2; xm2 = xm1; xm1 = x0;
    }
}

extern "C" void kernel_launch(void* const* d_in, const int* in_sizes, int n_in,
                              void* d_out, int out_size, void* d_ws, size_t ws_size,
                              hipStream_t stream) {
    const float* x    = (const float*)d_in[0];   // hidden_states [B,S,H]
    const float* w    = (const float*)d_in[1];   // weight [H,K]
    const float* mask = (const float*)d_in[2];   // attention_mask_2d [B,S]
    float* y = (float*)d_out;

    dim3 grid(H4_ / TPB, S_ / T_, B_);           // (2, 256, 4)
    budgie_dwconv1d_kernel<<<grid, TPB, 0, stream>>>(x, w, mask, y);
}

// Round 3
// 239.194 us; speedup vs baseline: 1.0083x; 1.0068x over previous
//
#include <hip/hip_runtime.h>

// Causal depthwise conv1d: y[b,s,h] = sum_j x[b, s-(K-1)+j, h] * w[h,j], * mask[b,s]
// B=4, S=4096, H=2048, K=4, fp32. Memory-bound.
// R2->R3: TPB 256->512 so ONE block covers a full 8 KiB h-row; block's aggregate
// address stream is fully sequential (16 rows = 128 KiB contiguous tile).
// R2 stalled at 2.6 TB/s (half of copy ceiling) with half-row blocks -> DRAM
// page-locality theory. Occupancy unchanged: 1024 blocks, 32 waves/CU.

constexpr int B_  = 4;
constexpr int S_  = 4096;
constexpr int H_  = 2048;
constexpr int T_  = 16;          // s-positions per block chunk
constexpr int H4_ = H_ / 4;      // 512 float4 channel-groups per (b,s) row
constexpr int TPB = 512;         // one thread per float4 group -> full row per block

__global__ __launch_bounds__(TPB) void budgie_dwconv1d_kernel(
    const float* __restrict__ x,     // [B,S,H]
    const float* __restrict__ w,     // [H,K]
    const float* __restrict__ mask,  // [B,S]
    float* __restrict__ y)           // [B,S,H]
{
    const int h4 = threadIdx.x;                      // channel-group id, 0..511
    const int s0 = blockIdx.x * T_;
    const int b  = blockIdx.y;

    const float4* __restrict__ x4 = (const float4*)x;
    const float4* __restrict__ w4 = (const float4*)w;
    float4* __restrict__ y4 = (float4*)y;

    // Per-channel taps: w[h, 0..3] is contiguous -> one float4 per channel.
    const int hbase = h4 * 4;
    const float4 w0 = w4[hbase + 0];
    const float4 w1 = w4[hbase + 1];
    const float4 w2 = w4[hbase + 2];
    const float4 w3 = w4[hbase + 3];

    const long base = (long)b * S_ * H4_ + h4;       // float4-unit index at s=0

    const float4 zero4 = make_float4(0.f, 0.f, 0.f, 0.f);
    // Preload sliding window x[s0-3], x[s0-2], x[s0-1] (zeros left of s=0).
    float4 xm3 = (s0 >= 3) ? x4[base + (long)(s0 - 3) * H4_] : zero4;
    float4 xm2 = (s0 >= 2) ? x4[base + (long)(s0 - 2) * H4_] : zero4;
    float4 xm1 = (s0 >= 1) ? x4[base + (long)(s0 - 1) * H4_] : zero4;

    #pragma unroll 8
    for (int t = 0; t < T_; ++t) {
        const int s = s0 + t;
        const float4 x0 = x4[base + (long)s * H4_];
        const float  m  = mask[b * S_ + s];

        float4 o;
        // channel c: y = x[s-3]*w[c].x + x[s-2]*w[c].y + x[s-1]*w[c].z + x[s]*w[c].w
        o.x = fmaf(xm3.x, w0.x, fmaf(xm2.x, w0.y, fmaf(xm1.x, w0.z, x0.x * w0.w)));
        o.y = fmaf(xm3.y, w1.x, fmaf(xm2.y, w1.y, fmaf(xm1.y, w1.z, x0.y * w1.w)));
        o.z = fmaf(xm3.z, w2.x, fmaf(xm2.z, w2.y, fmaf(xm1.z, w2.z, x0.z * w2.w)));
        o.w = fmaf(xm3.w, w3.x, fmaf(xm2.w, w3.y, fmaf(xm1.w, w3.z, x0.w * w3.w)));
        o.x *= m; o.y *= m; o.z *= m; o.w *= m;

        y4[base + (long)s * H4_] = o;

        xm3 = xm2; xm2 = xm1; xm1 = x0;
    }
}

extern "C" void kernel_launch(void* const* d_in, const int* in_sizes, int n_in,
                              void* d_out, int out_size, void* d_ws, size_t ws_size,
                              hipStream_t stream) {
    const float* x    = (const float*)d_in[0];   // hidden_states [B,S,H]
    const float* w    = (const float*)d_in[1];   // weight [H,K]
    const float* mask = (const float*)d_in[2];   // attention_mask_2d [B,S]
    float* y = (float*)d_out;

    dim3 grid(S_ / T_, B_);                      // (256, 4) = 1024 blocks
    budgie_dwconv1d_kernel<<<grid, TPB, 0, stream>>>(x, w, mask, y);
}